// Round 6
// baseline (968.569 us; speedup 1.0000x reference)
//
#include <hip/hip_runtime.h>
#include <hip/hip_bf16.h>

#define NNODES 100000
#define NEDGES 1600000
#define EPSBN 1e-5f

// CSR build via bucketed counting sort
#define BKT_SHIFT 9
#define NODES_PER_BKT 512
#define NBKT 196
#define NCHUNK 256
#define CHUNK 6250
#define SRC_MASK 0x1FFFF
#define NSLOT 64

typedef unsigned short u16;
typedef unsigned int u32;
typedef __bf16 bf16x8 __attribute__((ext_vector_type(8)));
typedef float floatx4 __attribute__((ext_vector_type(4)));

__device__ __forceinline__ u16 f2bf(float f) {
    unsigned int u = __float_as_uint(f);
    unsigned int r = (u + 0x7fffu + ((u >> 16) & 1u)) >> 16;
    return (u16)r;
}
__device__ __forceinline__ float bflo(unsigned int u) { return __uint_as_float(u << 16); }
__device__ __forceinline__ float bfhi(unsigned int u) { return __uint_as_float(u & 0xffff0000u); }

// ---------------- CSR build: bucketed counting sort ----------------

__global__ __launch_bounds__(256) void k_hist(const int* __restrict__ ei, int* __restrict__ histT) {
    __shared__ int h[NBKT];
    int tid = threadIdx.x;
    if (tid < NBKT) h[tid] = 0;
    __syncthreads();
    int base = blockIdx.x * CHUNK;
    for (int e = base + tid; e < base + CHUNK; e += 256) {
        int d = ei[NEDGES + e];
        atomicAdd(&h[d >> BKT_SHIFT], 1);
    }
    __syncthreads();
    if (tid < NBKT) histT[tid * NCHUNK + blockIdx.x] = h[tid];
}

__global__ __launch_bounds__(256) void k_bbase(const int* __restrict__ histT, int* __restrict__ bbase,
                                               int* __restrict__ rowptr) {
    __shared__ int sdata[256];
    int tid = threadIdx.x;
    int s = 0;
    if (tid < NBKT) {
        for (int g = 0; g < NCHUNK; ++g) s += histT[tid * NCHUNK + g];
    }
    int val = s;
    sdata[tid] = val;
    __syncthreads();
    for (int off = 1; off < 256; off <<= 1) {
        int add = (tid >= off) ? sdata[tid - off] : 0;
        __syncthreads();
        val += add;
        sdata[tid] = val;
        __syncthreads();
    }
    if (tid < NBKT) bbase[tid] = val - s;
    if (tid == 0) { bbase[NBKT] = NEDGES; rowptr[NNODES] = NEDGES; }
}

__global__ __launch_bounds__(256) void k_bscan(const int* __restrict__ histT, const int* __restrict__ bbase,
                                               int* __restrict__ offT) {
    __shared__ int sdata[256];
    int b = blockIdx.x;
    int g = threadIdx.x;
    int v = histT[b * NCHUNK + g];
    int val = v;
    sdata[g] = val;
    __syncthreads();
    for (int off = 1; off < 256; off <<= 1) {
        int add = (g >= off) ? sdata[g - off] : 0;
        __syncthreads();
        val += add;
        sdata[g] = val;
        __syncthreads();
    }
    offT[b * NCHUNK + g] = bbase[b] + (val - v);
}

__global__ __launch_bounds__(256) void k_scatter(const int* __restrict__ ei, const int* __restrict__ offT,
                                                 u32* __restrict__ rec) {
    __shared__ int cur[NBKT];
    int tid = threadIdx.x;
    if (tid < NBKT) cur[tid] = offT[tid * NCHUNK + blockIdx.x];
    __syncthreads();
    int base = blockIdx.x * CHUNK;
    for (int e = base + tid; e < base + CHUNK; e += 256) {
        int s = ei[e];
        int d = ei[NEDGES + e];
        int b = d >> BKT_SHIFT;
        int p = atomicAdd(&cur[b], 1);
        rec[p] = ((u32)(d & (NODES_PER_BKT - 1)) << 17) | (u32)s;
    }
}

__global__ __launch_bounds__(256) void k_bfill(const u32* __restrict__ rec, const int* __restrict__ bbase,
                                               int* __restrict__ rowptr, float* __restrict__ dinv,
                                               int* __restrict__ colsrc) {
    __shared__ int cnt[NODES_PER_BKT];
    __shared__ int sdata[256];
    int tid = threadIdx.x;
    int b = blockIdx.x;
    int n0 = b * NODES_PER_BKT;
    int r0 = bbase[b], r1 = bbase[b + 1];
    cnt[2 * tid] = 0;
    cnt[2 * tid + 1] = 0;
    __syncthreads();
    for (int r = r0 + tid; r < r1; r += 256) {
        atomicAdd(&cnt[rec[r] >> 17], 1);
    }
    __syncthreads();
    int c0 = cnt[2 * tid], c1 = cnt[2 * tid + 1];
    int ps = c0 + c1;
    int val = ps;
    sdata[tid] = val;
    __syncthreads();
    for (int off = 1; off < 256; off <<= 1) {
        int add = (tid >= off) ? sdata[tid - off] : 0;
        __syncthreads();
        val += add;
        sdata[tid] = val;
        __syncthreads();
    }
    int e0 = val - ps;
    int e1 = e0 + c0;
    int na = n0 + 2 * tid, nb2 = n0 + 2 * tid + 1;
    if (na < NNODES) {
        rowptr[na] = r0 + e0;
        dinv[na] = rsqrtf((float)(c0 + 1));
    }
    if (nb2 < NNODES) {
        rowptr[nb2] = r0 + e1;
        dinv[nb2] = rsqrtf((float)(c1 + 1));
    }
    cnt[2 * tid] = r0 + e0;
    cnt[2 * tid + 1] = r0 + e1;
    __syncthreads();
    for (int r = r0 + tid; r < r1; r += 256) {
        u32 u = rec[r];
        int p = atomicAdd(&cnt[u >> 17], 1);
        colsrc[p] = (int)(u & SRC_MASK);
    }
}

// ---------------- pack all W into B-fragment layout ----------------

template <int COUT>
__device__ __forceinline__ void packone(const float* __restrict__ W, u16* __restrict__ Wp, int f) {
    constexpr int CT = COUT / 16;
    if (f >= 4 * CT * 64) return;
    int ks = f / (CT * 64);
    int ct = (f / 64) % CT;
    int lane = f % 64;
    int quad = lane >> 4, mm = lane & 15;
#pragma unroll
    for (int j = 0; j < 8; ++j) {
        float v = W[(size_t)(ks * 32 + quad * 8 + j) * COUT + ct * 16 + mm];
        Wp[(size_t)f * 8 + j] = f2bf(v);
    }
}

__global__ __launch_bounds__(256) void k_packW_all(const float* __restrict__ W1, const float* __restrict__ W2,
                                                   const float* __restrict__ W3, u16* __restrict__ Wp1,
                                                   u16* __restrict__ Wp2, u16* __restrict__ Wp3) {
    int b = blockIdx.x;
    if (b < 8) packone<128>(W1, Wp1, b * 256 + threadIdx.x);
    else if (b < 16) packone<128>(W2, Wp2, (b - 8) * 256 + threadIdx.x);
    else packone<64>(W3, Wp3, (b - 16) * 256 + threadIdx.x);
}

// ---------------- MFMA GEMM ----------------
// Bout (slab-major [CT][N][16] bf16) = dinv[r] * act(X)[r,:] @ W
// X: fp32 row-major (BF16A=false) or bf16 slab-major [8][N][16] (BF16A=true)
// act = relu(scale*x+shift) if AFFINE; WRITEH: also write act(X) fp32 row-major to Hout.

template <int COUT, bool BF16A, bool AFFINE, bool WRITEH>
__global__ __launch_bounds__(256) void k_mfma_gemm(const void* __restrict__ Xin, const u16* __restrict__ Wp,
                                                   const float* __restrict__ dinv,
                                                   const float* __restrict__ scale, const float* __restrict__ shift,
                                                   u16* __restrict__ Bout, float* __restrict__ Hout) {
    constexpr int CT = COUT / 16;
    const int wave = threadIdx.x >> 6;
    const int lane = threadIdx.x & 63;
    const int quad = lane >> 4;
    const int m = lane & 15;
    const int rowbase = blockIdx.x * 64 + wave * 16;
    const int arow = rowbase + m;
    const bool rv = arow < NNODES;
    floatx4 acc[CT];
#pragma unroll
    for (int ct = 0; ct < CT; ++ct) acc[ct] = floatx4{0.f, 0.f, 0.f, 0.f};
#pragma unroll
    for (int ks = 0; ks < 4; ++ks) {
        const int k0 = ks * 32 + quad * 8;
        float xv[8];
        if (BF16A) {
            uint4 q = make_uint4(0u, 0u, 0u, 0u);
            if (rv) {
                const u16* base = (const u16*)Xin + ((size_t)((k0 >> 4) * NNODES + arow)) * 16 + (k0 & 15);
                q = *(const uint4*)base;
            }
            xv[0] = bflo(q.x); xv[1] = bfhi(q.x);
            xv[2] = bflo(q.y); xv[3] = bfhi(q.y);
            xv[4] = bflo(q.z); xv[5] = bfhi(q.z);
            xv[6] = bflo(q.w); xv[7] = bfhi(q.w);
        } else {
            float4 xa = make_float4(0.f, 0.f, 0.f, 0.f), xb = xa;
            if (rv) {
                xa = *(const float4*)((const float*)Xin + (size_t)arow * 128 + k0);
                xb = *(const float4*)((const float*)Xin + (size_t)arow * 128 + k0 + 4);
            }
            xv[0] = xa.x; xv[1] = xa.y; xv[2] = xa.z; xv[3] = xa.w;
            xv[4] = xb.x; xv[5] = xb.y; xv[6] = xb.z; xv[7] = xb.w;
        }
        if (AFFINE) {
            float4 sa = *(const float4*)(scale + k0), sb = *(const float4*)(scale + k0 + 4);
            float4 ha = *(const float4*)(shift + k0), hb = *(const float4*)(shift + k0 + 4);
            xv[0] = fmaxf(fmaf(xv[0], sa.x, ha.x), 0.f);
            xv[1] = fmaxf(fmaf(xv[1], sa.y, ha.y), 0.f);
            xv[2] = fmaxf(fmaf(xv[2], sa.z, ha.z), 0.f);
            xv[3] = fmaxf(fmaf(xv[3], sa.w, ha.w), 0.f);
            xv[4] = fmaxf(fmaf(xv[4], sb.x, hb.x), 0.f);
            xv[5] = fmaxf(fmaf(xv[5], sb.y, hb.y), 0.f);
            xv[6] = fmaxf(fmaf(xv[6], sb.z, hb.z), 0.f);
            xv[7] = fmaxf(fmaf(xv[7], sb.w, hb.w), 0.f);
        }
        if (WRITEH && rv) {
            *(float4*)(Hout + (size_t)arow * 128 + k0) = make_float4(xv[0], xv[1], xv[2], xv[3]);
            *(float4*)(Hout + (size_t)arow * 128 + k0 + 4) = make_float4(xv[4], xv[5], xv[6], xv[7]);
        }
        union { u16 h[8]; bf16x8 v; } ua;
#pragma unroll
        for (int j = 0; j < 8; ++j) ua.h[j] = f2bf(xv[j]);
#pragma unroll
        for (int ct = 0; ct < CT; ++ct) {
            uint4 bv = *(const uint4*)(Wp + ((size_t)(ks * CT + ct) * 64 + lane) * 8);
            bf16x8 b = *(const bf16x8*)&bv;
            acc[ct] = __builtin_amdgcn_mfma_f32_16x16x32_bf16(ua.v, b, acc[ct], 0, 0, 0);
        }
    }
    float dv[4];
#pragma unroll
    for (int reg = 0; reg < 4; ++reg) {
        int r = rowbase + quad * 4 + reg;
        dv[reg] = (r < NNODES) ? dinv[r] : 0.f;
    }
#pragma unroll
    for (int ct = 0; ct < CT; ++ct) {
#pragma unroll
        for (int reg = 0; reg < 4; ++reg) {
            int r = rowbase + quad * 4 + reg;
            if (r < NNODES) Bout[((size_t)(ct * NNODES + r)) * 16 + m] = f2bf(dv[reg] * acc[ct][reg]);
        }
    }
}

// ---------------- Slabbed aggregation (XCD-local L2 working set) ----------------
// Bs: bf16 slab-major [8][N][16]. slab = blockIdx&7 -> pins each 3.2MB slab to one XCD.
// As out: bf16 slab-major. Out[d] = dinv[d]*(B[d] + sum_s B[s]) + bias. Slot 0 = self-loop.

template <bool STATS>
__global__ __launch_bounds__(256) void k_aggs128(const u16* __restrict__ Bs, const float* __restrict__ dinv,
                                                 const int* __restrict__ rowptr, const int* __restrict__ colsrc,
                                                 const float* __restrict__ bias, u16* __restrict__ As,
                                                 float* __restrict__ slots) {
    const int slab = blockIdx.x & 7;
    const int wave = threadIdx.x >> 6;
    const int node = (blockIdx.x >> 3) * 4 + wave;
    const int lane = threadIdx.x & 63;
    const int g = lane >> 3;   // edge slot 0..7
    const int c8 = lane & 7;   // channel pair: channels slab*16 + 2*c8 (+1)
    const u32* B = (const u32*)Bs + (size_t)slab * NNODES * 8;
    const int beg = rowptr[node];
    const int L = rowptr[node + 1] - beg + 1;  // edges + self
    float a0 = 0.f, a1 = 0.f, b0 = 0.f, b1 = 0.f;
    for (int it = 0; it < L; it += 16) {
        int i0 = it + g, i1 = it + 8 + g;
        float w0 = (i0 < L) ? 1.f : 0.f;
        float w1 = (i1 < L) ? 1.f : 0.f;
        i0 = min(i0, L - 1);
        i1 = min(i1, L - 1);
        int x0 = min(beg + max(i0, 1) - 1, NEDGES - 1);
        int x1 = min(beg + max(i1, 1) - 1, NEDGES - 1);
        int s0 = colsrc[x0];
        int s1 = colsrc[x1];
        if (i0 == 0) s0 = node;
        if (i1 == 0) s1 = node;
        u32 q0 = B[(size_t)s0 * 8 + c8];
        u32 q1 = B[(size_t)s1 * 8 + c8];
        a0 += w0 * bflo(q0); a1 += w0 * bfhi(q0);
        b0 += w1 * bflo(q1); b1 += w1 * bfhi(q1);
    }
    a0 += b0; a1 += b1;
    a0 += __shfl_xor(a0, 8);  a1 += __shfl_xor(a1, 8);
    a0 += __shfl_xor(a0, 16); a1 += __shfl_xor(a1, 16);
    a0 += __shfl_xor(a0, 32); a1 += __shfl_xor(a1, 32);
    if (g == 0) {
        const float dv = dinv[node];
        const int ch = slab * 16 + 2 * c8;
        float o0 = dv * a0 + bias[ch];
        float o1 = dv * a1 + bias[ch + 1];
        ((u32*)As)[((size_t)(slab * NNODES + node)) * 8 + c8] = (u32)f2bf(o0) | ((u32)f2bf(o1) << 16);
        if (STATS) {
            float* slot = slots + (size_t)(node & (NSLOT - 1)) * 256;
            atomicAdd(&slot[ch], o0);
            atomicAdd(&slot[ch + 1], o1);
            atomicAdd(&slot[128 + ch], o0 * o0);
            atomicAdd(&slot[128 + ch + 1], o1 * o1);
        }
    }
}

// 64-channel variant: 4 slabs x 2 node-halves; writes fp32 row-major out.
__global__ __launch_bounds__(256) void k_aggs64(const u16* __restrict__ Bs, const float* __restrict__ dinv,
                                                const int* __restrict__ rowptr, const int* __restrict__ colsrc,
                                                const float* __restrict__ bias, float* __restrict__ Out) {
    const int cls = blockIdx.x & 7;
    const int slab = cls >> 1;
    const int half = cls & 1;
    const int wave = threadIdx.x >> 6;
    const int node = (blockIdx.x >> 3) * 4 + wave + half * (NNODES / 2);
    const int lane = threadIdx.x & 63;
    const int g = lane >> 3;
    const int c8 = lane & 7;
    const u32* B = (const u32*)Bs + (size_t)slab * NNODES * 8;
    const int beg = rowptr[node];
    const int L = rowptr[node + 1] - beg + 1;
    float a0 = 0.f, a1 = 0.f, b0 = 0.f, b1 = 0.f;
    for (int it = 0; it < L; it += 16) {
        int i0 = it + g, i1 = it + 8 + g;
        float w0 = (i0 < L) ? 1.f : 0.f;
        float w1 = (i1 < L) ? 1.f : 0.f;
        i0 = min(i0, L - 1);
        i1 = min(i1, L - 1);
        int x0 = min(beg + max(i0, 1) - 1, NEDGES - 1);
        int x1 = min(beg + max(i1, 1) - 1, NEDGES - 1);
        int s0 = colsrc[x0];
        int s1 = colsrc[x1];
        if (i0 == 0) s0 = node;
        if (i1 == 0) s1 = node;
        u32 q0 = B[(size_t)s0 * 8 + c8];
        u32 q1 = B[(size_t)s1 * 8 + c8];
        a0 += w0 * bflo(q0); a1 += w0 * bfhi(q0);
        b0 += w1 * bflo(q1); b1 += w1 * bfhi(q1);
    }
    a0 += b0; a1 += b1;
    a0 += __shfl_xor(a0, 8);  a1 += __shfl_xor(a1, 8);
    a0 += __shfl_xor(a0, 16); a1 += __shfl_xor(a1, 16);
    a0 += __shfl_xor(a0, 32); a1 += __shfl_xor(a1, 32);
    if (g == 0) {
        const float dv = dinv[node];
        const int ch = slab * 16 + 2 * c8;
        float2 o;
        o.x = dv * a0 + bias[ch];
        o.y = dv * a1 + bias[ch + 1];
        *(float2*)(Out + (size_t)node * 64 + ch) = o;
    }
}

// ---------------- BN finalize ----------------

__global__ void k_bn_final(const float* __restrict__ slots, const float* __restrict__ g,
                           const float* __restrict__ be, float* __restrict__ scale, float* __restrict__ shift) {
    int c = threadIdx.x;  // 128 threads
    float s = 0.f, q = 0.f;
    for (int k = 0; k < NSLOT; ++k) {
        s += slots[(size_t)k * 256 + c];
        q += slots[(size_t)k * 256 + 128 + c];
    }
    float mean = s * (1.0f / NNODES);
    float var = q * (1.0f / NNODES) - mean * mean;
    float istd = rsqrtf(var + EPSBN);
    float sc = g[c] * istd;
    scale[c] = sc;
    shift[c] = be[c] - sc * mean;
}

// ---------------- launch ----------------

extern "C" void kernel_launch(void* const* d_in, const int* in_sizes, int n_in,
                              void* d_out, int out_size, void* d_ws, size_t ws_size,
                              hipStream_t stream) {
    const float* x   = (const float*)d_in[0];
    const float* W1  = (const float*)d_in[1];
    const float* b1  = (const float*)d_in[2];
    const float* g1  = (const float*)d_in[3];
    const float* be1 = (const float*)d_in[4];
    const float* W2  = (const float*)d_in[5];
    const float* b2  = (const float*)d_in[6];
    const float* g2  = (const float*)d_in[7];
    const float* be2 = (const float*)d_in[8];
    const float* W3  = (const float*)d_in[9];
    const float* b3  = (const float*)d_in[10];
    const int* ei    = (const int*)d_in[11];

    float* out_h = (float*)d_out;                        // [N,128] h2 fp32
    float* out_o = (float*)d_out + (size_t)NNODES * 128; // [N,64]  conv3 out fp32

    char* w = (char*)d_ws;
    u16* As = (u16*)w;         w += (size_t)NNODES * 128 * 2;   // bf16 post-agg, slab-major [8][N][16]
    u16* Bm = (u16*)w;         w += (size_t)NNODES * 128 * 2;   // bf16 messages, slab-major
    float* dinv = (float*)w;   w += (size_t)NNODES * 4;
    int* rowptr = (int*)w;     w += (size_t)(NNODES + 32) * 4;
    int* colsrc = (int*)w;     w += (size_t)(NEDGES + 8) * 4;
    int* bbase = (int*)w;      w += (NBKT + 4) * 4;
    float* slots1 = (float*)w; w += (size_t)NSLOT * 256 * 4;
    float* slots2 = (float*)w; w += (size_t)NSLOT * 256 * 4;
    float* scale = (float*)w;  w += 128 * 4;
    float* shift = (float*)w;  w += 128 * 4;
    u16* Wp1 = (u16*)w;        w += 128 * 128 * 2;
    u16* Wp2 = (u16*)w;        w += 128 * 128 * 2;
    u16* Wp3 = (u16*)w;        w += 128 * 64 * 2;

    // Build-phase scratch aliased onto buffers dead until layer 1:
    u32* rec  = (u32*)As;                       // [NEDGES] (As first written by agg1)
    int* histT = (int*)Bm;                      // [NBKT*NCHUNK] (Bm first written by gemm1)
    int* offT  = (int*)Bm + NBKT * NCHUNK;

    hipMemsetAsync(slots1, 0, (size_t)2 * NSLOT * 256 * 4, stream);

    k_packW_all<<<20, 256, 0, stream>>>(W1, W2, W3, Wp1, Wp2, Wp3);

    // CSR build
    k_hist<<<NCHUNK, 256, 0, stream>>>(ei, histT);
    k_bbase<<<1, 256, 0, stream>>>(histT, bbase, rowptr);
    k_bscan<<<NBKT, 256, 0, stream>>>(histT, bbase, offT);
    k_scatter<<<NCHUNK, 256, 0, stream>>>(ei, offT, rec);
    k_bfill<<<NBKT, 256, 0, stream>>>(rec, bbase, rowptr, dinv, colsrc);

    const int GB = (NNODES + 63) / 64;          // 1563
    const int AB128 = (NNODES / 4) * 8;         // 200000 (slab = blockIdx&7)
    const int AB64 = (NNODES / 8) * 8;          // 100000 (4 slabs x 2 halves)

    // Layer 1: x fp32 -> Bm -> As (+stats1)
    k_mfma_gemm<128, false, false, false><<<GB, 256, 0, stream>>>(x, Wp1, dinv, nullptr, nullptr, Bm, nullptr);
    k_aggs128<true><<<AB128, 256, 0, stream>>>(Bm, dinv, rowptr, colsrc, b1, As, slots1);
    k_bn_final<<<1, 128, 0, stream>>>(slots1, g1, be1, scale, shift);

    // Layer 2: As (BN1+ReLU inline) -> Bm -> As (+stats2)
    k_mfma_gemm<128, true, true, false><<<GB, 256, 0, stream>>>(As, Wp2, dinv, scale, shift, Bm, nullptr);
    k_aggs128<true><<<AB128, 256, 0, stream>>>(Bm, dinv, rowptr, colsrc, b2, As, slots2);
    k_bn_final<<<1, 128, 0, stream>>>(slots2, g2, be2, scale, shift);

    // Layer 3: As (BN2+ReLU inline, h2 -> out_h) -> Bm64 -> out_o
    k_mfma_gemm<64, true, true, true><<<GB, 256, 0, stream>>>(As, Wp3, dinv, scale, shift, Bm, out_h);
    k_aggs64<<<AB64, 256, 0, stream>>>(Bm, dinv, rowptr, colsrc, b3, out_o);
}